// Round 8
// baseline (675.960 us; speedup 1.0000x reference)
//
#include <hip/hip_runtime.h>
#include <cstdint>
#include <cstddef>

#define M_DIM 2048
#define N_DIM 4096
#define K_DIM 20000
#define KP    20480                 /* K padded to multiple of 64 (zero-filled) */
#define NTILEF 320                  /* KP / 64 K-tiles (full K per WG) */
#define WBT_BYTES  167772160UL      /* 4096*20480*2 : bf16 W^T (N x KP) */
#define XB_OFFSET  167772160UL      /* bf16 x (M x KP) after Wbt */

typedef __attribute__((ext_vector_type(8))) short short8;
typedef __attribute__((ext_vector_type(2))) short short2v;
typedef __attribute__((ext_vector_type(4))) float float4v;
typedef __attribute__((ext_vector_type(8))) unsigned short ushort8;

__device__ __forceinline__ unsigned short f2bf_rne(float f) {
    union { float f; unsigned int u; } v; v.f = f;
    unsigned int u = v.u;
    u += 0x7FFFu + ((u >> 16) & 1u);   // round-to-nearest-even
    return (unsigned short)(u >> 16);
}

__device__ __forceinline__ float bf2f(unsigned short h) {
    union { unsigned int u; float f; } v;
    v.u = ((unsigned int)h) << 16;
    return v.f;
}

__device__ __forceinline__ void gload_lds16(const void* g, void* l) {
    __builtin_amdgcn_global_load_lds(
        (const __attribute__((address_space(1))) void*)g,
        (__attribute__((address_space(3))) void*)l, 16, 0, 0);
}

// ---- 0. zero Wbt at streaming-store rate ----
__global__ void zero_wbt_kernel(float4* __restrict__ p) {
    size_t t = (size_t)blockIdx.x * 256 + threadIdx.x;
    float4 z; z.x = 0.f; z.y = 0.f; z.z = 0.f; z.w = 0.f;
    #pragma unroll
    for (int i = 0; i < 20; ++i)
        p[t + (size_t)i * (2048 * 256)] = z;
}

// ---- 1. scatter-add COO directly into bf16 W^T (N_DIM x KP row-major) ----
__global__ void scatter_bf16_kernel(const float* __restrict__ kv,
                                    const int* __restrict__ ind,
                                    unsigned int* __restrict__ W, int nnz) {
    int t = blockIdx.x * blockDim.x + threadIdx.x;
    if (t >= nnz) return;
    int r = ind[2 * t];      // input_dim index (K)
    int c = ind[2 * t + 1];  // units index (N)
    float v = kv[t];
    size_t elem = (size_t)c * KP + r;
    unsigned int* word = &W[elem >> 1];
    const bool hi = (elem & 1) != 0;
    unsigned short hbits = f2bf_rne(v);
#if __has_builtin(__builtin_amdgcn_global_atomic_fadd_v2bf16)
    short2v val;
    val[0] = hi ? (short)0 : (short)hbits;
    val[1] = hi ? (short)hbits : (short)0;
    __builtin_amdgcn_global_atomic_fadd_v2bf16(
        (__attribute__((address_space(1))) short2v*)word, val);
#else
    unsigned int expected = 0u;
    unsigned int desired  = hi ? ((unsigned int)hbits << 16) : (unsigned int)hbits;
    for (;;) {
        unsigned int old = atomicCAS(word, expected, desired);
        if (old == expected) break;
        expected = old;
        unsigned short hcur = hi ? (unsigned short)(old >> 16)
                                 : (unsigned short)(old & 0xFFFFu);
        unsigned short nh = f2bf_rne(bf2f(hcur) + v);
        desired = hi ? ((old & 0x0000FFFFu) | ((unsigned int)nh << 16))
                     : ((old & 0xFFFF0000u) | (unsigned int)nh);
    }
#endif
}

// ---- 2. fp32 -> bf16 convert for x, writes K-pad zeros itself ----
__global__ void convert_kernel(const float* __restrict__ src,
                               unsigned short* __restrict__ dst) {
    size_t t = (size_t)blockIdx.x * 256 + threadIdx.x;
    int row = (int)(t / 2560);
    int c8  = (int)(t % 2560);
    ushort8 o;
    if (c8 < 2500) {
        const float4* sv = (const float4*)(src + (size_t)row * K_DIM + (size_t)c8 * 8);
        float4 a = sv[0];
        float4 b = sv[1];
        o[0] = f2bf_rne(a.x); o[1] = f2bf_rne(a.y);
        o[2] = f2bf_rne(a.z); o[3] = f2bf_rne(a.w);
        o[4] = f2bf_rne(b.x); o[5] = f2bf_rne(b.y);
        o[6] = f2bf_rne(b.z); o[7] = f2bf_rne(b.w);
    } else {
        o = (ushort8)0;
    }
    *(ushort8*)(dst + (size_t)row * KP + (size_t)c8 * 8) = o;
}

// ---- 3. 256x128-tile FULL-K GEMM + fused bias/tanh epilogue ----
// Carries the HW-proven round-4 machinery (swizzle, staging lane map, phase
// skeleton, counted vmcnt) to a full-K tile so Cp and the combine kernel
// disappear. Grid (32,8) = 256 WGs = 1/CU. 8 waves 4Mx2N, per-wave 64x64.
// LDS 96 KiB = 2 bufs x (A 32KB: 256 rows x 128B | B 16KB: 128 rows).
// Swizzle: 16B chunk c of row r at slot c^(r&7) (conflict-free, rounds 1/4).
// Per tile, 2 phases (kh0, kh1), each {12|4 ds_reads, stage, s_barrier,
// lgkmcnt(0), setprio(1) 16 MFMA setprio(0), [vmcnt(2) at P2], s_barrier}:
//  P1 reads kh0-A + BOTH kh of B from BUF; stages next tile's A (4 gloads)
//     into the OTHER buffer (safe: its A-reads finished at prev tile's end
//     barrier).  P2 reads kh1-A only (B reused from P1's regs); stages tile
//     t+2's B (2 gloads) into THIS buffer's B-slab (safe: B last read in P1,
//     covered by P1's lgkmcnt(0)+barrier).
// vmcnt(2) at P2 end waits (t+1).B and (t+1).A, leaves (t+2).B in flight --
// never drains in the main loop.
__global__ __launch_bounds__(512, 2) void gemm_fullk_kernel(
    const unsigned short* __restrict__ A,
    const unsigned short* __restrict__ Bt,
    const float* __restrict__ bias,
    float* __restrict__ out) {

    __shared__ unsigned short L[49152];    // 98304 B

    const int t    = threadIdx.x;
    const int w    = t >> 6;
    const int l    = t & 63;
    const int quad = l >> 4;
    const int r16  = l & 15;
    const int wm   = w >> 1;               // 0..3
    const int wn   = w & 1;                // 0..1

    const int m0 = blockIdx.y * 256;
    const int n0 = blockIdx.x * 128;

    // staging lane mapping: row sub-index lr8 = l>>3, chunk sl = (l&7)^(l>>3)
    const int lr8 = l >> 3;
    const int sl  = (l & 7) ^ lr8;
    const int w1024 = w << 10;

    const unsigned short* pA0 = A  + (size_t)(m0 +   0 + w * 8 + lr8) * KP + sl * 8;
    const unsigned short* pA1 = A  + (size_t)(m0 +  64 + w * 8 + lr8) * KP + sl * 8;
    const unsigned short* pA2 = A  + (size_t)(m0 + 128 + w * 8 + lr8) * KP + sl * 8;
    const unsigned short* pA3 = A  + (size_t)(m0 + 192 + w * 8 + lr8) * KP + sl * 8;
    const unsigned short* pB0 = Bt + (size_t)(n0 +   0 + w * 8 + lr8) * KP + sl * 8;
    const unsigned short* pB1 = Bt + (size_t)(n0 +  64 + w * 8 + lr8) * KP + sl * 8;

    char* Lb = (char*)L;

    // buffer layout (byte offsets): buf b at b*49152; A slab [0,32K), B [32K,48K)
#define STG_A(OB, Q, P) do { \
    gload_lds16(P, Lb + (OB) + (Q) * 8192 + w1024); P += 64; } while (0)
#define STG_B(OB, Q, P) do { \
    gload_lds16(P, Lb + (OB) + 32768 + (Q) * 8192 + w1024); P += 64; } while (0)

    // read offsets: byte = row*128 + ((chunk)^(row&7))*16, chunk = kh*4+quad
    const int h   = r16 & 7;
    const int so0 = ((quad ^ h) << 4);          // kh = 0
    const int so1 = (((4 | quad) ^ h) << 4);    // kh = 1
    const int aoff = wm * 8192 + r16 * 128;     // + i*2048
    const int boff = 32768 + wn * 8192 + r16 * 128;   // + j*2048

    float4v acc[4][4];
#pragma unroll
    for (int i = 0; i < 4; ++i)
#pragma unroll
        for (int j = 0; j < 4; ++j)
            acc[i][j] = (float4v){0.f, 0.f, 0.f, 0.f};

    short8 bfr[4][2], af[4];

#define VM2 asm volatile("s_waitcnt vmcnt(2)" ::: "memory")

#define TILE(BUF, OB) do { \
    { /* P1: kh0 MFMA; read A kh0 + B both kh; stage (t+1).A -> OB */ \
      const char* base_ = Lb + (BUF); \
      _Pragma("unroll") \
      for (int j = 0; j < 4; ++j) { \
          bfr[j][0] = *(const short8*)(base_ + boff + j * 2048 + so0); \
          bfr[j][1] = *(const short8*)(base_ + boff + j * 2048 + so1); \
      } \
      _Pragma("unroll") \
      for (int i = 0; i < 4; ++i) \
          af[i] = *(const short8*)(base_ + aoff + i * 2048 + so0); \
      STG_A(OB, 0, pA0); STG_A(OB, 1, pA1); \
      STG_A(OB, 2, pA2); STG_A(OB, 3, pA3); \
      __builtin_amdgcn_s_barrier(); \
      asm volatile("s_waitcnt lgkmcnt(0)" ::: "memory"); \
      __builtin_amdgcn_s_setprio(1); \
      _Pragma("unroll") \
      for (int i = 0; i < 4; ++i) \
          _Pragma("unroll") \
          for (int j = 0; j < 4; ++j) \
              acc[i][j] = __builtin_amdgcn_mfma_f32_16x16x32_bf16( \
                  af[i], bfr[j][0], acc[i][j], 0, 0, 0); \
      __builtin_amdgcn_s_setprio(0); \
      __builtin_amdgcn_s_barrier(); \
    } \
    { /* P2: kh1 MFMA; read A kh1; stage (t+2).B -> BUF B-slab */ \
      const char* base_ = Lb + (BUF); \
      _Pragma("unroll") \
      for (int i = 0; i < 4; ++i) \
          af[i] = *(const short8*)(base_ + aoff + i * 2048 + so1); \
      STG_B(BUF, 0, pB0); STG_B(BUF, 1, pB1); \
      __builtin_amdgcn_s_barrier(); \
      asm volatile("s_waitcnt lgkmcnt(0)" ::: "memory"); \
      __builtin_amdgcn_s_setprio(1); \
      _Pragma("unroll") \
      for (int i = 0; i < 4; ++i) \
          _Pragma("unroll") \
          for (int j = 0; j < 4; ++j) \
              acc[i][j] = __builtin_amdgcn_mfma_f32_16x16x32_bf16( \
                  af[i], bfr[j][1], acc[i][j], 0, 0, 0); \
      __builtin_amdgcn_s_setprio(0); \
      VM2; \
      __builtin_amdgcn_s_barrier(); \
    } \
} while (0)

    // prologue: tile0 A+B (6 gloads) into buf0, tile1.B (2) into buf1;
    // vmcnt(2) waits tile0's 6, leaves tile1.B in flight (= steady state).
    STG_A(0, 0, pA0); STG_A(0, 1, pA1); STG_A(0, 2, pA2); STG_A(0, 3, pA3);
    STG_B(0, 0, pB0); STG_B(0, 1, pB1);
    STG_B(49152, 0, pB0); STG_B(49152, 1, pB1);
    asm volatile("s_waitcnt vmcnt(2)" ::: "memory");
    __builtin_amdgcn_s_barrier();

    // 320 tiles = 160 iterations x 2. Tail stages overrun K by <=2 tiles:
    // reads stay within the allocated workspace, data never consumed.
#pragma unroll 1
    for (int it = 0; it < NTILEF / 2; ++it) {
        TILE(0, 49152);
        TILE(49152, 0);
    }
    // drain in-flight LDS DMA before wave exit
    asm volatile("s_waitcnt vmcnt(0)" ::: "memory");

    // fused epilogue: out = tanh(acc + bias), fp32 direct.
    // C/D layout: col = lane&15, row = quad*4 + reg.
#pragma unroll
    for (int j = 0; j < 4; ++j) {
        const int col = n0 + wn * 64 + j * 16 + r16;
        const float bv = bias[col];
#pragma unroll
        for (int i = 0; i < 4; ++i) {
            const int row = m0 + wm * 64 + i * 16 + quad * 4;
#pragma unroll
            for (int r = 0; r < 4; ++r)
                out[(size_t)(row + r) * N_DIM + col] = tanhf(acc[i][j][r] + bv);
        }
    }
#undef TILE
#undef STG_A
#undef STG_B
#undef VM2
}

extern "C" void kernel_launch(void* const* d_in, const int* in_sizes, int n_in,
                              void* d_out, int out_size, void* d_ws, size_t ws_size,
                              hipStream_t stream) {
    const float* x    = (const float*)d_in[0];
    const float* kv   = (const float*)d_in[1];
    const float* bias = (const float*)d_in[2];
    const int*   ind  = (const int*)d_in[3];
    const int nnz = in_sizes[1];

    unsigned short* Wbt = (unsigned short*)d_ws;                        // bf16 W^T (N x KP)
    unsigned short* xb  = (unsigned short*)((char*)d_ws + XB_OFFSET);   // bf16 x (M x KP)

    // 1. zero bf16 W^T (incl. K-pad)
    zero_wbt_kernel<<<2048, 256, 0, stream>>>((float4*)Wbt);
    // 2. scatter-add straight into bf16 W^T (HW packed-bf16 atomic add)
    scatter_bf16_kernel<<<(nnz + 255) / 256, 256, 0, stream>>>(
        kv, ind, (unsigned int*)Wbt, nnz);
    // 3. x fp32 -> bf16 (writes its own K-pad zeros)
    convert_kernel<<<(M_DIM * (KP / 8)) / 256, 256, 0, stream>>>(x, xb);
    // 4. full-K GEMM with fused bias+tanh epilogue (no Cp, no combine)
    gemm_fullk_kernel<<<dim3(N_DIM / 128, M_DIM / 256), 512, 0, stream>>>(
        xb, Wbt, bias, (float*)d_out);
}